// Round 1
// baseline (123.296 us; speedup 1.0000x reference)
//
#include <hip/hip_runtime.h>
#include <hip/hip_bf16.h>
#include <cstdint>

// Problem constants
#define BATCH 8
#define NREP 12306          // N
#define OUTC 192            // TS^3*3

__device__ __forceinline__ float gelu_exact(float x) {
    return 0.5f * x * (1.0f + erff(x * 0.70710678118654752f));
}
__device__ __forceinline__ float sigmoidf_(float x) {
    return 1.0f / (1.0f + __expf(-x));
}

// Wave-per-row GEMV over 8 batches.
// in:  [8][K] activations, W: [R][K], bias: [R], out: [8][R]
// block = 256 threads = 4 waves; each wave computes one output row for all 8 batches.
template <int K, int R, int ACT> // ACT: 0 = gelu(exact), 1 = sigmoid
__global__ __launch_bounds__(256) void gemv_layer(const float* __restrict__ in,
                                                  const float* __restrict__ W,
                                                  const float* __restrict__ bias,
                                                  float* __restrict__ out) {
    __shared__ float s_in[BATCH * K];
    for (int i = threadIdx.x; i < BATCH * K; i += 256) s_in[i] = in[i];
    __syncthreads();

    const int wave = threadIdx.x >> 6;
    const int lane = threadIdx.x & 63;
    const int row  = blockIdx.x * 4 + wave;
    if (row >= R) return;

    constexpr int NV = K / 256;  // float4 loads per lane (K is 256/512/1024)
    float4 wv[NV];
    const float4* Wrow = reinterpret_cast<const float4*>(W + (size_t)row * K);
#pragma unroll
    for (int i = 0; i < NV; ++i) wv[i] = Wrow[i * 64 + lane];

    float acc[BATCH];
#pragma unroll
    for (int b = 0; b < BATCH; ++b) {
        const float4* sb = reinterpret_cast<const float4*>(s_in + b * K);
        float a = 0.0f;
#pragma unroll
        for (int i = 0; i < NV; ++i) {
            const float4 iv = sb[i * 64 + lane];
            a += wv[i].x * iv.x + wv[i].y * iv.y + wv[i].z * iv.z + wv[i].w * iv.w;
        }
        acc[b] = a;
    }

    // full-wave butterfly reduce (64 lanes) for each batch accumulator
#pragma unroll
    for (int b = 0; b < BATCH; ++b) {
#pragma unroll
        for (int s = 32; s > 0; s >>= 1) acc[b] += __shfl_xor(acc[b], s, 64);
    }

    if (lane == 0) {
        const float bb = bias[row];
#pragma unroll
        for (int b = 0; b < BATCH; ++b) {
            float x = acc[b] + bb;
            out[b * R + row] = (ACT == 0) ? gelu_exact(x) : sigmoidf_(x);
        }
    }
}

// One block per (b, p) run: writes NREP copies of o[b*OUTC + p] contiguously.
__global__ __launch_bounds__(256) void broadcast_kernel(const float* __restrict__ o,
                                                        float* __restrict__ out) {
    const int bp = blockIdx.x;          // 0 .. BATCH*OUTC-1
    const float v = o[bp];
    const size_t e0 = (size_t)bp * NREP;
    float* p = out + e0;
    const int t = threadIdx.x;

    // Align to 16B (run start element offset mod 4 is 0 or 2)
    const int mis  = (int)(e0 & 3);
    const int head = mis ? (4 - mis) : 0;
    if (t < head) p[t] = v;

    const int n_main4 = (NREP - head) >> 2;      // number of float4 stores
    float4 vv = make_float4(v, v, v, v);
    float4* p4 = reinterpret_cast<float4*>(p + head);
    for (int j = t; j < n_main4; j += 256) p4[j] = vv;

    const int done = head + (n_main4 << 2);
    const int tail = NREP - done;
    if (t < tail) p[done + t] = v;
}

extern "C" void kernel_launch(void* const* d_in, const int* in_sizes, int n_in,
                              void* d_out, int out_size, void* d_ws, size_t ws_size,
                              hipStream_t stream) {
    const float* latent = (const float*)d_in[0];   // [8][1][256]
    const float* W1 = (const float*)d_in[1];       // [512][256]
    const float* b1 = (const float*)d_in[2];
    const float* W2 = (const float*)d_in[3];       // [1024][512]
    const float* b2 = (const float*)d_in[4];
    const float* W3 = (const float*)d_in[5];       // [512][1024]
    const float* b3 = (const float*)d_in[6];
    const float* W4 = (const float*)d_in[7];       // [192][512]
    const float* b4 = (const float*)d_in[8];
    float* out = (float*)d_out;

    float* ws = (float*)d_ws;
    float* h1 = ws;                       // 8*512
    float* h2 = h1 + BATCH * 512;         // 8*1024
    float* h3 = h2 + BATCH * 1024;        // 8*512
    float* o  = h3 + BATCH * 512;         // 8*192

    gemv_layer< 256,  512, 0><<<512 / 4,  256, 0, stream>>>(latent, W1, b1, h1);
    gemv_layer< 512, 1024, 0><<<1024 / 4, 256, 0, stream>>>(h1,     W2, b2, h2);
    gemv_layer<1024,  512, 0><<<512 / 4,  256, 0, stream>>>(h2,     W3, b3, h3);
    gemv_layer< 512,  192, 1><<<192 / 4,  256, 0, stream>>>(h3,     W4, b4, o);

    broadcast_kernel<<<BATCH * OUTC, 256, 0, stream>>>(o, out);
}